// Round 2
// baseline (658.945 us; speedup 1.0000x reference)
//
#include <hip/hip_runtime.h>
#include <hip/hip_bf16.h>

// Problem constants (B=8,S=4096,D=1024, A=16, C=8, dc=64, apc=2)
#define DIM 1024
#define NANCH 16
#define NCOMP 8
#define DC 64
#define DC2 128
#define EPS_LN 1e-5f
#define EPS_NORM 1e-12f

typedef __bf16 bf16x8 __attribute__((ext_vector_type(8)));
typedef float f32x4 __attribute__((ext_vector_type(4)));

// ---------------- Kernel 1: normalize anchors -> f32 ----------------
__global__ __launch_bounds__(256) void knorm_anchors(
    const float* __restrict__ anchors, float* __restrict__ An) {
  int a = blockIdx.x, t = threadIdx.x;
  int lane = t & 63, wid = t >> 6;
  __shared__ float red[4];
  float v[4]; float ss = 0.f;
#pragma unroll
  for (int i = 0; i < 4; i++) {
    v[i] = anchors[a * DIM + t + 256 * i];
    ss += v[i] * v[i];
  }
  for (int off = 32; off; off >>= 1) ss += __shfl_down(ss, off);
  if (lane == 0) red[wid] = ss;
  __syncthreads();
  float inv = 1.f / fmaxf(sqrtf(red[0] + red[1] + red[2] + red[3]), EPS_NORM);
#pragma unroll
  for (int i = 0; i < 4; i++) An[a * DIM + t + 256 * i] = v[i] * inv;
}

// ------- Kernel 2: transpose Wp (512x1024 f32) -> WpT (1024x512 bf16) ----
__global__ __launch_bounds__(256) void ktrans(
    const float* __restrict__ Wp, __hip_bfloat16* __restrict__ WpT) {
  __shared__ float tile[64][65];
  int bj = blockIdx.x, bk = blockIdx.y;  // grid (16, 8)
  int tx = threadIdx.x & 63, ty = threadIdx.x >> 6;
#pragma unroll
  for (int i = 0; i < 16; i++) {
    int r = ty + 4 * i;  // local k
    tile[r][tx] = Wp[(size_t)(bk * 64 + r) * DIM + bj * 64 + tx];
  }
  __syncthreads();
#pragma unroll
  for (int i = 0; i < 16; i++) {
    int r = ty + 4 * i;  // local j
    WpT[(size_t)(bj * 64 + r) * 512 + bk * 64 + tx] = __float2bfloat16(tile[tx][r]);
  }
}

// ---------------- Kernel 3: per-token pipeline -> y (N x 512 bf16) -------
__global__ __launch_bounds__(256) void ktoken(
    const float* __restrict__ x, const float* __restrict__ An,
    const float* __restrict__ ln_g, const float* __restrict__ ln_b,
    const float* __restrict__ W1, const float* __restrict__ b1,
    const float* __restrict__ W2, const float* __restrict__ b2,
    const float* __restrict__ cg, const float* __restrict__ cb,
    __hip_bfloat16* __restrict__ yout) {
  int n = blockIdx.x, t = threadIdx.x;
  int lane = t & 63, wid = t >> 6;
  __shared__ float sh[DIM];     // h, then reused for u
  __shared__ float tri_s[NANCH];
  __shared__ float red[8];

  const float* xr = x + (size_t)n * DIM;
  float xv[4], s = 0.f, s2 = 0.f;
#pragma unroll
  for (int i = 0; i < 4; i++) {
    float v = xr[t + 256 * i];
    xv[i] = v; s += v; s2 += v * v;
  }
  for (int off = 32; off; off >>= 1) { s += __shfl_down(s, off); s2 += __shfl_down(s2, off); }
  if (lane == 0) { red[wid] = s; red[4 + wid] = s2; }
  __syncthreads();
  float mu = (red[0] + red[1] + red[2] + red[3]) * (1.f / DIM);
  float ex2 = (red[4] + red[5] + red[6] + red[7]) * (1.f / DIM);
  float rstd = rsqrtf(ex2 - mu * mu + EPS_LN);

  float hv[4], ss = 0.f;
#pragma unroll
  for (int i = 0; i < 4; i++) {
    int d = t + 256 * i;
    float h = (xv[i] - mu) * rstd * ln_g[d] + ln_b[d];
    hv[i] = h; ss += h * h;
  }
  for (int off = 32; off; off >>= 1) ss += __shfl_down(ss, off);
  __syncthreads();  // all reads of red[] done before rewrite
  if (lane == 0) red[wid] = ss;
  __syncthreads();
  float inv = 1.f / fmaxf(sqrtf(red[0] + red[1] + red[2] + red[3]), EPS_NORM);
#pragma unroll
  for (int i = 0; i < 4; i++) sh[t + 256 * i] = hv[i] * inv;
  __syncthreads();

  // tri: wave w handles anchors 4w..4w+3
  float dp[4] = {0.f, 0.f, 0.f, 0.f};
  for (int i = 0; i < 16; i++) {
    float h = sh[lane + 64 * i];
#pragma unroll
    for (int a = 0; a < 4; a++)
      dp[a] += h * An[(size_t)(wid * 4 + a) * DIM + lane + 64 * i];
  }
#pragma unroll
  for (int a = 0; a < 4; a++) {
    float v = dp[a];
    for (int off = 32; off; off >>= 1) v += __shfl_down(v, off);
    if (lane == 0) tri_s[wid * 4 + a] = 1.f - v;
  }
  __syncthreads();

  // u[k][e] = relu(tri[k]*W1[k,0,e] + tri[8+k]*W1[k,1,e] + b1[k,e])^2 -> sh
#pragma unroll
  for (int r = 0; r < 4; r++) {
    int idx = t + 256 * r;           // = k*128 + e
    int k = idx >> 7, e = idx & 127;
    float uu = tri_s[k] * W1[k * 256 + e] +
               tri_s[8 + k] * W1[k * 256 + 128 + e] +
               b1[idx];
    uu = fmaxf(uu, 0.f);
    sh[idx] = uu * uu;
  }
  __syncthreads();

  // y[k][d] = sum_e u[k][e]*W2[k][e][d] + b2[k][d]; then per-comp LN over d
  float yv[2];
#pragma unroll
  for (int r = 0; r < 2; r++) {
    int o = t + 256 * r;             // = k*64 + d ; wave holds one full comp
    int k = o >> 6, d = o & 63;
    float acc = b2[o];
    const float* w2 = W2 + k * (DC2 * DC) + d;
    for (int e = 0; e < DC2; e++) acc += sh[k * DC2 + e] * w2[e * DC];
    yv[r] = acc;
  }
#pragma unroll
  for (int r = 0; r < 2; r++) {
    float v = yv[r], sY = v, sY2 = v * v;
    for (int off = 32; off; off >>= 1) { sY += __shfl_down(sY, off); sY2 += __shfl_down(sY2, off); }
    sY = __shfl(sY, 0); sY2 = __shfl(sY2, 0);
    float muY = sY * (1.f / DC);
    float rs = rsqrtf(sY2 * (1.f / DC) - muY * muY + EPS_LN);
    int o = t + 256 * r;
    float yl = (v - muY) * rs * cg[o] + cb[o];
    yout[(size_t)n * 512 + o] = __float2bfloat16(yl);
  }
}

// ---------------- Kernel 4: out = x + sig(gate)*(y @ Wp + bp) -----------
// y: [N][512] bf16, WpT: [1024][512] bf16. Block tile 128x128, 4 waves 2x2,
// each wave 64x64 via 4x4 mfma_f32_16x16x32_bf16. BK=64, LDS rows padded to
// 72 elems (144 B, still 16B-aligned per row).
#define LDP 72
__global__ __launch_bounds__(256) void kgemm(
    const __hip_bfloat16* __restrict__ Y, const __hip_bfloat16* __restrict__ WpT,
    const float* __restrict__ x, const float* __restrict__ bp,
    const float* __restrict__ gate, float* __restrict__ out) {
  __shared__ alignas(16) __hip_bfloat16 As[128 * LDP];
  __shared__ alignas(16) __hip_bfloat16 Bs[128 * LDP];
  int t = threadIdx.x, lane = t & 63, wid = t >> 6;
  int bm = blockIdx.x, bj = blockIdx.y;
  int wm = (wid >> 1) * 64, wj = (wid & 1) * 64;
  int l15 = lane & 15, quad = lane >> 4;

  f32x4 acc[4][4] = {};

  for (int k0 = 0; k0 < 512; k0 += 64) {
#pragma unroll
    for (int it = 0; it < 4; it++) {
      int c = it * 256 + t;
      int row = c >> 3, col = (c & 7) * 8;
      *(uint4*)(&As[row * LDP + col]) =
          *(const uint4*)(&Y[(size_t)(bm * 128 + row) * 512 + k0 + col]);
      *(uint4*)(&Bs[row * LDP + col]) =
          *(const uint4*)(&WpT[(size_t)(bj * 128 + row) * 512 + k0 + col]);
    }
    __syncthreads();
#pragma unroll
    for (int kk = 0; kk < 64; kk += 32) {
      bf16x8 af[4], bfr[4];
#pragma unroll
      for (int i = 0; i < 4; i++) {
        af[i]  = *(const bf16x8*)(&As[(wm + i * 16 + l15) * LDP + kk + quad * 8]);
        bfr[i] = *(const bf16x8*)(&Bs[(wj + i * 16 + l15) * LDP + kk + quad * 8]);
      }
#pragma unroll
      for (int i = 0; i < 4; i++)
#pragma unroll
        for (int j = 0; j < 4; j++)
          acc[i][j] = __builtin_amdgcn_mfma_f32_16x16x32_bf16(af[i], bfr[j], acc[i][j], 0, 0, 0);
    }
    __syncthreads();
  }

  // epilogue
  float sg[4], bpv[4];
#pragma unroll
  for (int j = 0; j < 4; j++) {
    int gc = bj * 128 + wj + j * 16 + l15;
    sg[j] = 1.f / (1.f + expf(-gate[gc]));
    bpv[j] = bp[gc];
  }
#pragma unroll
  for (int i = 0; i < 4; i++) {
#pragma unroll
    for (int j = 0; j < 4; j++) {
      int gc = bj * 128 + wj + j * 16 + l15;
#pragma unroll
      for (int r = 0; r < 4; r++) {
        int gr = bm * 128 + wm + i * 16 + quad * 4 + r;   // D row=(lane>>4)*4+reg
        size_t idx = (size_t)gr * DIM + gc;
        out[idx] = x[idx] + sg[j] * (acc[i][j][r] + bpv[j]);
      }
    }
  }
}

extern "C" void kernel_launch(void* const* d_in, const int* in_sizes, int n_in,
                              void* d_out, int out_size, void* d_ws, size_t ws_size,
                              hipStream_t stream) {
  const float* x       = (const float*)d_in[0];
  const float* anchors = (const float*)d_in[1];
  const float* ln_g    = (const float*)d_in[2];
  const float* ln_b    = (const float*)d_in[3];
  const float* W1      = (const float*)d_in[4];
  const float* b1      = (const float*)d_in[5];
  const float* W2      = (const float*)d_in[6];
  const float* b2      = (const float*)d_in[7];
  const float* cg      = (const float*)d_in[8];
  const float* cb      = (const float*)d_in[9];
  const float* Wp      = (const float*)d_in[10];
  const float* bp      = (const float*)d_in[11];
  const float* gate    = (const float*)d_in[12];

  int N = in_sizes[0] / DIM;  // 32768 tokens

  char* w = (char*)d_ws;
  float* An             = (float*)w;                           // 16*1024*4 = 64 KB
  __hip_bfloat16* WpT   = (__hip_bfloat16*)(w + (64 << 10));   // 1024*512*2 = 1 MB
  __hip_bfloat16* Yb    = (__hip_bfloat16*)(w + (64 << 10) + (1 << 20));  // N*512*2 = 32 MB

  knorm_anchors<<<NANCH, 256, 0, stream>>>(anchors, An);
  ktrans<<<dim3(16, 8), 256, 0, stream>>>(Wp, WpT);
  ktoken<<<N, 256, 0, stream>>>(x, An, ln_g, ln_b, W1, b1, W2, b2, cg, cb, Yb);
  kgemm<<<dim3(N / 128, DIM / 128), 256, 0, stream>>>(Yb, WpT, x, bp, gate,
                                                      (float*)d_out);
}

// Round 3
// 358.107 us; speedup vs baseline: 1.8401x; 1.8401x over previous
//
#include <hip/hip_runtime.h>
#include <hip/hip_bf16.h>

// Problem constants (B=8,S=4096,D=1024, A=16, C=8, dc=64, apc=2)
#define DIM 1024
#define NANCH 16
#define NCOMP 8
#define DC 64
#define DC2 128
#define EPS_LN 1e-5f
#define EPS_NORM 1e-12f

typedef __bf16 bf16x8 __attribute__((ext_vector_type(8)));
typedef float f32x4 __attribute__((ext_vector_type(4)));

// ---------------- Kernel 1: normalize anchors -> f32 ----------------
__global__ __launch_bounds__(256) void knorm_anchors(
    const float* __restrict__ anchors, float* __restrict__ An) {
  int a = blockIdx.x, t = threadIdx.x;
  int lane = t & 63, wid = t >> 6;
  __shared__ float red[4];
  float v[4]; float ss = 0.f;
#pragma unroll
  for (int i = 0; i < 4; i++) {
    v[i] = anchors[a * DIM + t + 256 * i];
    ss += v[i] * v[i];
  }
  for (int off = 32; off; off >>= 1) ss += __shfl_down(ss, off);
  if (lane == 0) red[wid] = ss;
  __syncthreads();
  float inv = 1.f / fmaxf(sqrtf(red[0] + red[1] + red[2] + red[3]), EPS_NORM);
#pragma unroll
  for (int i = 0; i < 4; i++) An[a * DIM + t + 256 * i] = v[i] * inv;
}

// ------- Kernel 2: transpose Wp (512x1024 f32) -> WpT (1024x512 bf16) ----
__global__ __launch_bounds__(256) void ktrans(
    const float* __restrict__ Wp, __hip_bfloat16* __restrict__ WpT) {
  __shared__ float tile[64][65];
  int bj = blockIdx.x, bk = blockIdx.y;  // grid (16, 8)
  int tx = threadIdx.x & 63, ty = threadIdx.x >> 6;
#pragma unroll
  for (int i = 0; i < 16; i++) {
    int r = ty + 4 * i;  // local k
    tile[r][tx] = Wp[(size_t)(bk * 64 + r) * DIM + bj * 64 + tx];
  }
  __syncthreads();
#pragma unroll
  for (int i = 0; i < 16; i++) {
    int r = ty + 4 * i;  // local j
    WpT[(size_t)(bj * 64 + r) * 512 + bk * 64 + tx] = __float2bfloat16(tile[tx][r]);
  }
}

// --- Kernel 2b: build B-fragment tables for W2 and An (bf16) -------------
// W2B[((k*4+nt)*4+ks)*512 + lane*8 + j] = W2[k][e=ks*32+(lane>>4)*8+j][n=nt*16+(lane&15)]
// AnB[ks*512 + lane*8 + j]             = An[a=lane&15][e=ks*32+(lane>>4)*8+j]
__global__ __launch_bounds__(256) void kprep(
    const float* __restrict__ W2, const float* __restrict__ An,
    __hip_bfloat16* __restrict__ W2B, __hip_bfloat16* __restrict__ AnB) {
  int id = blockIdx.x * 256 + threadIdx.x;
  if (id < 65536) {
    int j = id & 7, lane = (id >> 3) & 63, ks = (id >> 9) & 3,
        nt = (id >> 11) & 3, k = id >> 13;
    int e = ks * 32 + (lane >> 4) * 8 + j;
    int n = nt * 16 + (lane & 15);
    W2B[id] = __float2bfloat16(W2[k * (DC2 * DC) + e * DC + n]);
  } else {
    int id2 = id - 65536;  // 16384 elems
    int j = id2 & 7, lane = (id2 >> 3) & 63, ks = id2 >> 9;  // ks in [0,32)
    int e = ks * 32 + (lane >> 4) * 8 + j;
    int a = lane & 15;
    AnB[id2] = __float2bfloat16(An[a * DIM + e]);
  }
}

// ---------------- Kernel 3: 16 tokens/block -> y (N x 512 bf16) ----------
// Phase A: LN + l2norm -> h (bf16, LDS). Phase B: tri = 1 - h@AnT via MFMA.
// Phase C: u = relu(...)^2 (overwrites h in LDS). Phase D: per-comp
// y = u@W2 via MFMA + b2 + LN(dc=64) -> yout.
#define LDA_H 1032  // 1024 + 8 bf16 pad: row stride 2064 B = 516 dw, 516%32=4
__global__ __launch_bounds__(256) void ktoken(
    const float* __restrict__ x, const __hip_bfloat16* __restrict__ AnB,
    const float* __restrict__ ln_g, const float* __restrict__ ln_b,
    const float* __restrict__ W1, const float* __restrict__ b1,
    const __hip_bfloat16* __restrict__ W2B, const float* __restrict__ b2,
    const float* __restrict__ cg, const float* __restrict__ cb,
    __hip_bfloat16* __restrict__ yout) {
  int t = threadIdx.x;
  int lane = t & 63, w = t >> 6;
  int l15 = lane & 15, quad = lane >> 4;
  int n0 = blockIdx.x * 16;

  __shared__ __hip_bfloat16 hu[16 * LDA_H];  // 33 KB: h, then u
  __shared__ float tri_s[16 * 16];           // [token][anchor]
  __shared__ float part[4 * 64 * 4];         // tri partial tiles

  // ---- Phase A: LN + l2norm for tokens w*4..w*4+3 (one wave each) ----
  float gv[16], bv[16];
#pragma unroll
  for (int i = 0; i < 16; i++) { gv[i] = ln_g[i * 64 + lane]; bv[i] = ln_b[i * 64 + lane]; }
#pragma unroll
  for (int it = 0; it < 4; it++) {
    int tok = w * 4 + it;
    const float* xr = x + (size_t)(n0 + tok) * DIM;
    float xv[16], s = 0.f, s2 = 0.f;
#pragma unroll
    for (int i = 0; i < 16; i++) {
      float v = xr[i * 64 + lane];
      xv[i] = v; s += v; s2 += v * v;
    }
#pragma unroll
    for (int off = 32; off; off >>= 1) { s += __shfl_xor(s, off); s2 += __shfl_xor(s2, off); }
    float mu = s * (1.f / DIM);
    float rstd = rsqrtf(s2 * (1.f / DIM) - mu * mu + EPS_LN);
    float ss = 0.f;
#pragma unroll
    for (int i = 0; i < 16; i++) {
      float h = (xv[i] - mu) * rstd * gv[i] + bv[i];
      xv[i] = h; ss += h * h;
    }
#pragma unroll
    for (int off = 32; off; off >>= 1) ss += __shfl_xor(ss, off);
    float inv = 1.f / fmaxf(sqrtf(ss), EPS_NORM);
#pragma unroll
    for (int i = 0; i < 16; i++)
      hu[tok * LDA_H + i * 64 + lane] = __float2bfloat16(xv[i] * inv);
  }
  __syncthreads();

  // ---- Phase B: tri[m][a] = 1 - sum_e h[m][e]*An[a][e], MFMA over K=1024 ----
  {
    f32x4 tacc = {0.f, 0.f, 0.f, 0.f};
#pragma unroll
    for (int ks = w * 8; ks < w * 8 + 8; ks++) {
      bf16x8 afr = *(const bf16x8*)(&hu[l15 * LDA_H + ks * 32 + quad * 8]);
      bf16x8 bfr = *(const bf16x8*)(&AnB[ks * 512 + lane * 8]);
      tacc = __builtin_amdgcn_mfma_f32_16x16x32_bf16(afr, bfr, tacc, 0, 0, 0);
    }
    *(f32x4*)(&part[(w * 64 + lane) * 4]) = tacc;
  }
  __syncthreads();
  {
    int ln = t & 63, rg = t >> 6;
    float v = part[(0 * 64 + ln) * 4 + rg] + part[(1 * 64 + ln) * 4 + rg] +
              part[(2 * 64 + ln) * 4 + rg] + part[(3 * 64 + ln) * 4 + rg];
    int m = (ln >> 4) * 4 + rg, a = ln & 15;
    tri_s[m * 16 + a] = 1.f - v;
  }
  __syncthreads();

  // ---- Phase C: u = relu(tri0*W1a + tri1*W1b + b1)^2 -> hu (bf16) ----
  {
    float w1a[4], w1b[4], b1v[4];
#pragma unroll
    for (int i = 0; i < 4; i++) {
      int idx = i * 256 + t, k = idx >> 7, e = idx & 127;
      w1a[i] = W1[k * 256 + e];
      w1b[i] = W1[k * 256 + 128 + e];
      b1v[i] = b1[idx];
    }
#pragma unroll
    for (int tok = 0; tok < 16; tok++) {
#pragma unroll
      for (int i = 0; i < 4; i++) {
        int idx = i * 256 + t, k = idx >> 7;
        float uu = tri_s[tok * 16 + k] * w1a[i] +
                   tri_s[tok * 16 + 8 + k] * w1b[i] + b1v[i];
        uu = fmaxf(uu, 0.f);
        hu[tok * LDA_H + idx] = __float2bfloat16(uu * uu);
      }
    }
  }
  __syncthreads();

  // ---- Phase D: per-comp y = u@W2 + b2, LN over dc=64, write ----
  // wave w handles comps 2w, 2w+1
#pragma unroll
  for (int kc = 0; kc < 2; kc++) {
    int k = w * 2 + kc;
    bf16x8 afr[4];
#pragma unroll
    for (int ks = 0; ks < 4; ks++)
      afr[ks] = *(const bf16x8*)(&hu[l15 * LDA_H + k * 128 + ks * 32 + quad * 8]);
    f32x4 acc[4] = {{0,0,0,0},{0,0,0,0},{0,0,0,0},{0,0,0,0}};
#pragma unroll
    for (int nt = 0; nt < 4; nt++) {
#pragma unroll
      for (int ks = 0; ks < 4; ks++) {
        bf16x8 bfr = *(const bf16x8*)(&W2B[(size_t)(((k * 4 + nt) * 4 + ks)) * 512 + lane * 8]);
        acc[nt] = __builtin_amdgcn_mfma_f32_16x16x32_bf16(afr[ks], bfr, acc[nt], 0, 0, 0);
      }
    }
    // add b2, LN over 64 (token m = quad*4+reg; its 64 vals live in this quad)
    float vals[4][4], s1[4] = {0,0,0,0}, s2[4] = {0,0,0,0};
#pragma unroll
    for (int nt = 0; nt < 4; nt++) {
      float b2v = b2[k * 64 + nt * 16 + l15];
#pragma unroll
      for (int r = 0; r < 4; r++) {
        float v = acc[nt][r] + b2v;
        vals[nt][r] = v; s1[r] += v; s2[r] += v * v;
      }
    }
#pragma unroll
    for (int r = 0; r < 4; r++) {
#pragma unroll
      for (int off = 1; off < 16; off <<= 1) {
        s1[r] += __shfl_xor(s1[r], off);
        s2[r] += __shfl_xor(s2[r], off);
      }
    }
#pragma unroll
    for (int r = 0; r < 4; r++) {
      float mu = s1[r] * (1.f / DC);
      float rs = rsqrtf(s2[r] * (1.f / DC) - mu * mu + EPS_LN);
      int tokrow = quad * 4 + r;
#pragma unroll
      for (int nt = 0; nt < 4; nt++) {
        int d = nt * 16 + l15;
        float yn = (vals[nt][r] - mu) * rs * cg[k * 64 + d] + cb[k * 64 + d];
        yout[(size_t)(n0 + tokrow) * 512 + k * 64 + d] = __float2bfloat16(yn);
      }
    }
  }
}

// ---------------- Kernel 4: out = x + sig(gate)*(y @ Wp + bp) -----------
#define LDP 72
__global__ __launch_bounds__(256) void kgemm(
    const __hip_bfloat16* __restrict__ Y, const __hip_bfloat16* __restrict__ WpT,
    const float* __restrict__ x, const float* __restrict__ bp,
    const float* __restrict__ gate, float* __restrict__ out) {
  __shared__ alignas(16) __hip_bfloat16 As[128 * LDP];
  __shared__ alignas(16) __hip_bfloat16 Bs[128 * LDP];
  int t = threadIdx.x, lane = t & 63, wid = t >> 6;
  int bm = blockIdx.x, bj = blockIdx.y;
  int wm = (wid >> 1) * 64, wj = (wid & 1) * 64;
  int l15 = lane & 15, quad = lane >> 4;

  f32x4 acc[4][4] = {};

  for (int k0 = 0; k0 < 512; k0 += 64) {
#pragma unroll
    for (int it = 0; it < 4; it++) {
      int c = it * 256 + t;
      int row = c >> 3, col = (c & 7) * 8;
      *(uint4*)(&As[row * LDP + col]) =
          *(const uint4*)(&Y[(size_t)(bm * 128 + row) * 512 + k0 + col]);
      *(uint4*)(&Bs[row * LDP + col]) =
          *(const uint4*)(&WpT[(size_t)(bj * 128 + row) * 512 + k0 + col]);
    }
    __syncthreads();
#pragma unroll
    for (int kk = 0; kk < 64; kk += 32) {
      bf16x8 af[4], bfr[4];
#pragma unroll
      for (int i = 0; i < 4; i++) {
        af[i]  = *(const bf16x8*)(&As[(wm + i * 16 + l15) * LDP + kk + quad * 8]);
        bfr[i] = *(const bf16x8*)(&Bs[(wj + i * 16 + l15) * LDP + kk + quad * 8]);
      }
#pragma unroll
      for (int i = 0; i < 4; i++)
#pragma unroll
        for (int j = 0; j < 4; j++)
          acc[i][j] = __builtin_amdgcn_mfma_f32_16x16x32_bf16(af[i], bfr[j], acc[i][j], 0, 0, 0);
    }
    __syncthreads();
  }

  float sg[4], bpv[4];
#pragma unroll
  for (int j = 0; j < 4; j++) {
    int gc = bj * 128 + wj + j * 16 + l15;
    sg[j] = 1.f / (1.f + expf(-gate[gc]));
    bpv[j] = bp[gc];
  }
#pragma unroll
  for (int i = 0; i < 4; i++) {
#pragma unroll
    for (int j = 0; j < 4; j++) {
      int gc = bj * 128 + wj + j * 16 + l15;
#pragma unroll
      for (int r = 0; r < 4; r++) {
        int gr = bm * 128 + wm + i * 16 + quad * 4 + r;   // D row=(lane>>4)*4+reg
        size_t idx = (size_t)gr * DIM + gc;
        out[idx] = x[idx] + sg[j] * (acc[i][j][r] + bpv[j]);
      }
    }
  }
}

extern "C" void kernel_launch(void* const* d_in, const int* in_sizes, int n_in,
                              void* d_out, int out_size, void* d_ws, size_t ws_size,
                              hipStream_t stream) {
  const float* x       = (const float*)d_in[0];
  const float* anchors = (const float*)d_in[1];
  const float* ln_g    = (const float*)d_in[2];
  const float* ln_b    = (const float*)d_in[3];
  const float* W1      = (const float*)d_in[4];
  const float* b1      = (const float*)d_in[5];
  const float* W2      = (const float*)d_in[6];
  const float* b2      = (const float*)d_in[7];
  const float* cg      = (const float*)d_in[8];
  const float* cb      = (const float*)d_in[9];
  const float* Wp      = (const float*)d_in[10];
  const float* bp      = (const float*)d_in[11];
  const float* gate    = (const float*)d_in[12];

  int N = in_sizes[0] / DIM;  // 32768 tokens

  char* w = (char*)d_ws;
  size_t off = 0;
  float* An           = (float*)(w + off);           off += 64 << 10;   // 64 KB
  __hip_bfloat16* WpT = (__hip_bfloat16*)(w + off);  off += 1 << 20;    // 1 MB
  __hip_bfloat16* W2B = (__hip_bfloat16*)(w + off);  off += 128 << 10;  // 128 KB
  __hip_bfloat16* AnB = (__hip_bfloat16*)(w + off);  off += 32 << 10;   // 32 KB
  __hip_bfloat16* Yb  = (__hip_bfloat16*)(w + off);                     // N*512*2 = 32 MB

  knorm_anchors<<<NANCH, 256, 0, stream>>>(anchors, An);
  ktrans<<<dim3(16, 8), 256, 0, stream>>>(Wp, WpT);
  kprep<<<320, 256, 0, stream>>>(W2, An, W2B, AnB);
  ktoken<<<N / 16, 256, 0, stream>>>(x, AnB, ln_g, ln_b, W1, b1, W2B, b2, cg, cb, Yb);
  kgemm<<<dim3(N / 128, DIM / 128), 256, 0, stream>>>(Yb, WpT, x, bp, gate,
                                                      (float*)d_out);
}